// Round 19
// baseline (373.239 us; speedup 1.0000x reference)
//
#include <hip/hip_runtime.h>
#include <hip/hip_bf16.h>

// Conv2d NCHW, stride=1, pad=1, N=16, C=8, K=8, H=W=1024, 3x3, fp32 in/out.
// Round 19 = round 18 (wave-private staging, ZERO barriers) with the asm
// constraint bug fixed: global_load writes its dest ASYNCHRONOUSLY, so all
// asm outputs must be EARLY-CLOBBER "=&v" (plain "=v" let the allocator
// overlap outputs with the live voff input -> corrupted addresses -> page
// fault; r15/r16 only worked by allocation luck, r17/r18 crashed).
// Structure: each wave owns 48x2 outputs, stages its own 4 rows x 56 units
// into its own LDS region (no cross-wave reads -> no __syncthreads at all),
// register-double-banked volatile-asm loads + counted vmcnt (32 loads +
// 3 stores/phase -> vmcnt(35) steady). 2-row packed MFMA math (r16-verified).

typedef __attribute__((ext_vector_type(8))) short short8;
typedef __attribute__((ext_vector_type(4))) float f32x4;

#define HH 1024
#define WW 1024
#define HWsz (1024*1024)
#define WVW 48          // output cols per wave
#define HB 8            // output rows per tile (4 waves x 2 rows)
#define URL 56          // staged 16B-units per row (in_w = w0-4+u, u=0..55)
#define RPW 4           // staged rows per wave
#define SPW (RPW*URL)   // 224 sites per wave
#define NIT 16          // h-tiles per block
#define GX 22           // w blocks: 21*48=1008, last overlaps at w0=976

__device__ __forceinline__ int pk2(float a, float b) {
    __hip_bfloat162 h = __float22bfloat162_rn(make_float2(a, b));  // v_cvt_pk_bf16_f32
    return *reinterpret_cast<int*>(&h);
}
__device__ __forceinline__ unsigned short f2bf(float f) {
    unsigned u = __float_as_uint(f);
    return (unsigned short)((u + 0x7FFFu + ((u >> 16) & 1u)) >> 16);   // RNE
}

__global__ __launch_bounds__(256) void conv3x3_wp2(
    const float* __restrict__ x,      // [16][8][1024][1024]
    const float* __restrict__ wgt,    // [8][8][3][3]
    const float* __restrict__ bias,   // [8]
    float* __restrict__ out)          // [16][8][1024][1024]
{
    __shared__ int4 lds[4 * SPW];     // wave wv owns lds[wv*SPW .. +223]

    const int tid  = threadIdx.x;
    const int lane = tid & 63;
    const int wv   = tid >> 6;        // wave 0..3: output rows 2wv, 2wv+1
    const int l15  = lane & 15;
    const int ch   = lane >> 4;

    const int wx    = blockIdx.x;     // 0..21
    const int strip = blockIdx.y;     // 0..7
    const int n     = blockIdx.z;     // 0..15
    const int w0    = (wx == GX - 1) ? (WW - WVW) : wx * WVW;
    const int htbase = strip * (NIT * HB);    // strip*128
    const int rowg0  = 2 * wv - 1;    // wave's first staged row rel. tile top

    const float* xn = x + (size_t)n * 8 * HWsz;
    const float* base0 = xn + 0 * (size_t)HWsz;
    const float* base1 = xn + 1 * (size_t)HWsz;
    const float* base2 = xn + 2 * (size_t)HWsz;
    const float* base3 = xn + 3 * (size_t)HWsz;
    const float* base4 = xn + 4 * (size_t)HWsz;
    const float* base5 = xn + 5 * (size_t)HWsz;
    const float* base6 = xn + 6 * (size_t)HWsz;
    const float* base7 = xn + 7 * (size_t)HWsz;

    // ---- K=96 slot map (verified r16): s = kh*24 + kw*8 + ci ----
    const int s0 = 8 * ch,      kh0 = s0 / 24, kw0 = (s0 % 24) / 8;
    const int s1 = 32 + 8 * ch, kh1 = s1 / 24, kw1 = (s1 % 24) / 8;
    const int s2 = 64 + 8 * ch, kh2 = s2 / 24, kw2 = (s2 % 24) / 8;
    const int off0 = kh0 * URL + kw0 + 3;
    const int off1 = kh1 * URL + kw1 + 3;
    const int off2 = kh2 * URL + kw2 + 3;

    // ---- B-fragments (verified r16): col l15 = hi*8+co ----
    const int hi  = l15 >> 3;
    const int co8 = l15 & 7;
    short8 b0, b1, b2;
    {
        const int ke0 = kh0 - hi, ke1 = kh1 - hi, ke2 = kh2 - hi;
        const bool v0 = (ke0 >= 0) && (ke0 <= 2);
        const bool v1 = (ke1 >= 0) && (ke1 <= 2);
        const bool v2 = (ke2 >= 0) && (ke2 <= 2);
#pragma unroll
        for (int j = 0; j < 8; ++j) {
            b0[j] = (short)(v0 ? f2bf(wgt[co8 * 72 + j * 9 + ke0 * 3 + kw0]) : 0);
            b1[j] = (short)(v1 ? f2bf(wgt[co8 * 72 + j * 9 + ke1 * 3 + kw1]) : 0);
            b2[j] = (short)(v2 ? f2bf(wgt[co8 * 72 + j * 9 + ke2 * 3 + kw2]) : 0);
        }
    }
    const float bv = bias[co8];

    // ---- per-lane staging site constants (4 sites: s = j*64+lane, clamped) ----
    int srow[4], gwc[4], lidx[4];
    bool wok[4];
#pragma unroll
    for (int j = 0; j < 4; ++j) {
        int s = j * 64 + lane;
        if (s > SPW - 1) s = SPW - 1;             // dup: same data, benign
        const int r  = s / URL;
        const int u  = s - r * URL;
        srow[j] = r;
        lidx[j] = wv * SPW + s;
        const int gwr = w0 - 4 + u;
        wok[j]  = ((unsigned)gwr < (unsigned)WW);
        gwc[j]  = (gwr < 0) ? 0 : ((gwr > WW - 1) ? WW - 1 : gwr);
    }

    float bkA[4][8], bkB[4][8];

    // issue 32 volatile asm dword loads; outputs EARLY-CLOBBER (async dest!)
#define LOADS(ht, bk)                                                        \
    {                                                                        \
        _Pragma("unroll")                                                    \
        for (int j = 0; j < 4; ++j) {                                        \
            const int gr  = (ht) + rowg0 + srow[j];                          \
            const int ghc = (gr < 0) ? 0 : ((gr > HH - 1) ? HH - 1 : gr);    \
            const unsigned voff = ((unsigned)(ghc * WW + gwc[j])) * 4u;      \
            asm volatile("global_load_dword %0, %8, %9\n\t"                  \
                         "global_load_dword %1, %8, %10\n\t"                 \
                         "global_load_dword %2, %8, %11\n\t"                 \
                         "global_load_dword %3, %8, %12\n\t"                 \
                         "global_load_dword %4, %8, %13\n\t"                 \
                         "global_load_dword %5, %8, %14\n\t"                 \
                         "global_load_dword %6, %8, %15\n\t"                 \
                         "global_load_dword %7, %8, %16"                     \
                         : "=&v"(bk[j][0]), "=&v"(bk[j][1]), "=&v"(bk[j][2]),\
                           "=&v"(bk[j][3]), "=&v"(bk[j][4]), "=&v"(bk[j][5]),\
                           "=&v"(bk[j][6]), "=&v"(bk[j][7])                  \
                         : "v"(voff), "s"(base0), "s"(base1), "s"(base2),    \
                           "s"(base3), "s"(base4), "s"(base5), "s"(base6),   \
                           "s"(base7)                                        \
                         : "memory");                                        \
        }                                                                    \
    }

    // convert + write into the wave's OWN LDS region (verified bf16 layout)
#define CONV(ht, bk)                                                         \
    {                                                                        \
        _Pragma("unroll")                                                    \
        for (int j = 0; j < 4; ++j) {                                        \
            const int gr = (ht) + rowg0 + srow[j];                           \
            const bool ok = ((unsigned)gr < (unsigned)HH) && wok[j];         \
            const float v0 = ok ? bk[j][0] : 0.0f;                           \
            const float v1 = ok ? bk[j][1] : 0.0f;                           \
            const float v2 = ok ? bk[j][2] : 0.0f;                           \
            const float v3 = ok ? bk[j][3] : 0.0f;                           \
            const float v4 = ok ? bk[j][4] : 0.0f;                           \
            const float v5 = ok ? bk[j][5] : 0.0f;                           \
            const float v6 = ok ? bk[j][6] : 0.0f;                           \
            const float v7 = ok ? bk[j][7] : 0.0f;                           \
            int4 pk;                                                         \
            pk.x = pk2(v0, v1);                                              \
            pk.y = pk2(v2, v3);                                              \
            pk.z = pk2(v4, v5);                                              \
            pk.w = pk2(v6, v7);                                              \
            lds[lidx[j]] = pk;                                               \
        }                                                                    \
    }

    // 2-row packed compute (verified r16), 3 w-tiles, wave-local region
#define BODY(ht)                                                             \
    {                                                                        \
        f32x4 acc[3];                                                        \
        _Pragma("unroll")                                                    \
        for (int wt = 0; wt < 3; ++wt) {                                     \
            acc[wt].x = bv; acc[wt].y = bv; acc[wt].z = bv; acc[wt].w = bv;  \
        }                                                                    \
        const int ub = wv * SPW + l15;                                       \
        _Pragma("unroll")                                                    \
        for (int wt = 0; wt < 3; ++wt) {                                     \
            const int u = ub + wt * 16;                                      \
            short8 a0 = *reinterpret_cast<const short8*>(&lds[u + off0]);    \
            short8 a1 = *reinterpret_cast<const short8*>(&lds[u + off1]);    \
            short8 a2 = *reinterpret_cast<const short8*>(&lds[u + off2]);    \
            f32x4 c = acc[wt];                                               \
            c = __builtin_amdgcn_mfma_f32_16x16x32_bf16(a0, b0, c, 0, 0, 0); \
            c = __builtin_amdgcn_mfma_f32_16x16x32_bf16(a1, b1, c, 0, 0, 0); \
            c = __builtin_amdgcn_mfma_f32_16x16x32_bf16(a2, b2, c, 0, 0, 0); \
            acc[wt] = c;                                                     \
        }                                                                    \
        float* op = out + ((size_t)n * 8 + co8) * HWsz                       \
                        + (size_t)((ht) + 2 * wv + hi) * WW + w0 + ch * 4;   \
        _Pragma("unroll")                                                    \
        for (int wt = 0; wt < 3; ++wt)                                       \
            *reinterpret_cast<float4*>(op + wt * 16) =                       \
                *reinterpret_cast<const float4*>(&acc[wt]);                  \
    }

    // ---- prologue ----
    LOADS(htbase, bkA);

    for (int k = 0; k < NIT; k += 2) {
        // ======== even: consume A, prefetch into B ========
        {
            const int ht = htbase + k * HB;
            LOADS(ht + HB, bkB);                       // tile k+1
            if (k == 0) {
                asm volatile("s_waitcnt vmcnt(32)" ::: "memory");
            } else {
                asm volatile("s_waitcnt vmcnt(35)" ::: "memory");
            }
            __builtin_amdgcn_sched_barrier(0);
            CONV(ht, bkA);
            asm volatile("s_waitcnt lgkmcnt(0)" ::: "memory");
            __builtin_amdgcn_sched_barrier(0);
            BODY(ht);                                  // 3 stores
        }
        // ======== odd: consume B, prefetch into A ========
        {
            const int ht = htbase + (k + 1) * HB;
            int t2 = k + 2; if (t2 > NIT - 1) t2 = NIT - 1;   // clamp tail
            LOADS(htbase + t2 * HB, bkA);              // tile k+2
            asm volatile("s_waitcnt vmcnt(35)" ::: "memory");
            __builtin_amdgcn_sched_barrier(0);
            CONV(ht, bkB);
            asm volatile("s_waitcnt lgkmcnt(0)" ::: "memory");
            __builtin_amdgcn_sched_barrier(0);
            BODY(ht);
        }
    }
#undef LOADS
#undef CONV
#undef BODY
}

extern "C" void kernel_launch(void* const* d_in, const int* in_sizes, int n_in,
                              void* d_out, int out_size, void* d_ws, size_t ws_size,
                              hipStream_t stream) {
    const float* x    = (const float*)d_in[0];
    const float* wgt  = (const float*)d_in[1];
    const float* bias = (const float*)d_in[2];
    float* out = (float*)d_out;

    dim3 grid(GX, 8, 16);   // (wx, strip, n) = 2816 blocks
    dim3 block(256, 1, 1);
    conv3x3_wp2<<<grid, block, 0, stream>>>(x, wgt, bias, out);
}

// Round 20
// 280.508 us; speedup vs baseline: 1.3306x; 1.3306x over previous
//
#include <hip/hip_runtime.h>
#include <hip/hip_bf16.h>

// Conv2d NCHW, stride=1, pad=1, N=16, C=8, K=8, H=W=1024, 3x3, fp32 in/out.
// Round 20 = r16 (best, 275us: barrier pipeline + volatile-asm staged loads
// + counted vmcnt + 2-row packed MFMA) with staging widened 4B -> 8B
// (dwordx2) and the r17/r18 crash fixed: global_load writes its dest
// ASYNCHRONOUSLY so asm outputs are EARLY-CLOBBER "=&v" (r19 confirmed the
// diagnosis). 16 dwordx2/thread (512B/wave-instr) replace 24 dword.
// Pair-1 clamped so every wave issues exactly 16 loads -> ledger: k0=16,
// steady=20 (16 next-loads + 4 prev-stores). Dup-pair LDS writes guarded.

typedef __attribute__((ext_vector_type(8))) short short8;
typedef __attribute__((ext_vector_type(4))) float f32x4;
typedef __attribute__((ext_vector_type(2))) float fx2;

#define HH 1024
#define WW 1024
#define HWsz (1024*1024)
#define WB 64           // output cols per tile
#define HB 8            // output rows per tile
#define SROWS 10        // staged input rows per tile
#define UROW 72         // bf16 16B-units per row (w0-4 .. w0+67)
#define PPR 36          // site-pairs per row (UROW/2)
#define NPAIRS (SROWS*PPR)    // 360
#define NIT 16          // h-tiles per block (strip = 128 rows)
#define NSITES (SROWS*UROW)   // 720

__device__ __forceinline__ int pk2(float a, float b) {
    __hip_bfloat162 h = __float22bfloat162_rn(make_float2(a, b));  // v_cvt_pk_bf16_f32
    return *reinterpret_cast<int*>(&h);
}
__device__ __forceinline__ unsigned short f2bf(float f) {
    unsigned u = __float_as_uint(f);
    return (unsigned short)((u + 0x7FFFu + ((u >> 16) & 1u)) >> 16);   // RNE
}

__global__ __launch_bounds__(256) void conv3x3_w2f(
    const float* __restrict__ x,      // [16][8][1024][1024]
    const float* __restrict__ wgt,    // [8][8][3][3]
    const float* __restrict__ bias,   // [8]
    float* __restrict__ out)          // [16][8][1024][1024]
{
    __shared__ int4 bfA[NSITES];      // 11520 B each
    __shared__ int4 bfB[NSITES];

    const int tid  = threadIdx.x;
    const int lane = tid & 63;
    const int wv   = tid >> 6;        // wave 0..3: output rows 2wv, 2wv+1
    const int l15  = lane & 15;
    const int ch   = lane >> 4;

    const int wx    = blockIdx.x;     // 0..15
    const int strip = blockIdx.y;     // 0..7
    const int n     = blockIdx.z;     // 0..15
    const int w0    = wx * WB;
    const int htbase = strip * (NIT * HB);    // strip*128

    const float* xn = x + (size_t)n * 8 * HWsz;
    const float* base0 = xn + 0 * (size_t)HWsz;
    const float* base1 = xn + 1 * (size_t)HWsz;
    const float* base2 = xn + 2 * (size_t)HWsz;
    const float* base3 = xn + 3 * (size_t)HWsz;
    const float* base4 = xn + 4 * (size_t)HWsz;
    const float* base5 = xn + 5 * (size_t)HWsz;
    const float* base6 = xn + 6 * (size_t)HWsz;
    const float* base7 = xn + 7 * (size_t)HWsz;

    // ---- K=96 slot map (verified r16): s = kh*24 + kw*8 + ci ----
    const int s0 = 8 * ch,      kh0 = s0 / 24, kw0 = (s0 % 24) / 8;
    const int s1 = 32 + 8 * ch, kh1 = s1 / 24, kw1 = (s1 % 24) / 8;
    const int s2 = 64 + 8 * ch, kh2 = s2 / 24, kw2 = (s2 % 24) / 8;
    const int off0 = kh0 * UROW + kw0 + 3;
    const int off1 = kh1 * UROW + kw1 + 3;
    const int off2 = kh2 * UROW + kw2 + 3;

    // ---- B-fragments (verified r16): col l15 = hi*8+co ----
    const int hi  = l15 >> 3;
    const int co8 = l15 & 7;
    short8 b0, b1, b2;
    {
        const int ke0 = kh0 - hi, ke1 = kh1 - hi, ke2 = kh2 - hi;
        const bool v0 = (ke0 >= 0) && (ke0 <= 2);
        const bool v1 = (ke1 >= 0) && (ke1 <= 2);
        const bool v2 = (ke2 >= 0) && (ke2 <= 2);
#pragma unroll
        for (int j = 0; j < 8; ++j) {
            b0[j] = (short)(v0 ? f2bf(wgt[co8 * 72 + j * 9 + ke0 * 3 + kw0]) : 0);
            b1[j] = (short)(v1 ? f2bf(wgt[co8 * 72 + j * 9 + ke1 * 3 + kw1]) : 0);
            b2[j] = (short)(v2 ? f2bf(wgt[co8 * 72 + j * 9 + ke2 * 3 + kw2]) : 0);
        }
    }
    const float bv = bias[co8];

    // ---- per-thread staging PAIR constants (2 pairs; pair1 clamped) ----
    int srow[2], gwc[2], ubase[2];
    bool oke[2], oko[2], wr[2];
#pragma unroll
    for (int j = 0; j < 2; ++j) {
        int p = (j == 0) ? tid : (256 + tid);
        wr[j] = (p < NPAIRS);                         // write-enable (no dup writes)
        if (p > NPAIRS - 1) p = NPAIRS - 1;           // clamp (loads only)
        const int r  = p / PPR;
        const int up = p - r * PPR;
        srow[j]  = r;
        ubase[j] = r * UROW + 2 * up;
        const int gwe = w0 - 4 + 2 * up;
        oke[j] = ((unsigned)gwe       < (unsigned)WW);
        oko[j] = ((unsigned)(gwe + 1) < (unsigned)WW);
        gwc[j] = (gwe < 0) ? 0 : ((gwe > WW - 2) ? WW - 2 : gwe);   // even -> 8B aligned
    }

    fx2 bkA[2][8], bkB[2][8];

    // 16 volatile asm dwordx2 loads; outputs EARLY-CLOBBER (async dest!)
#define LOADS(htile, bk)                                                     \
    {                                                                        \
        _Pragma("unroll")                                                    \
        for (int j = 0; j < 2; ++j) {                                        \
            const int gr  = (htile) - 1 + srow[j];                           \
            const int ghc = (gr < 0) ? 0 : ((gr > HH - 1) ? HH - 1 : gr);    \
            const unsigned voff = ((unsigned)(ghc * WW + gwc[j])) * 4u;      \
            asm volatile("global_load_dwordx2 %0, %8, %9\n\t"                \
                         "global_load_dwordx2 %1, %8, %10\n\t"               \
                         "global_load_dwordx2 %2, %8, %11\n\t"               \
                         "global_load_dwordx2 %3, %8, %12\n\t"               \
                         "global_load_dwordx2 %4, %8, %13\n\t"               \
                         "global_load_dwordx2 %5, %8, %14\n\t"               \
                         "global_load_dwordx2 %6, %8, %15\n\t"               \
                         "global_load_dwordx2 %7, %8, %16"                   \
                         : "=&v"(bk[j][0]), "=&v"(bk[j][1]), "=&v"(bk[j][2]),\
                           "=&v"(bk[j][3]), "=&v"(bk[j][4]), "=&v"(bk[j][5]),\
                           "=&v"(bk[j][6]), "=&v"(bk[j][7])                  \
                         : "v"(voff), "s"(base0), "s"(base1), "s"(base2),    \
                           "s"(base3), "s"(base4), "s"(base5), "s"(base6),   \
                           "s"(base7)                                        \
                         : "memory");                                        \
        }                                                                    \
    }

#define CONV(htile, bk, bfb)                                                 \
    {                                                                        \
        _Pragma("unroll")                                                    \
        for (int j = 0; j < 2; ++j) {                                        \
            if (wr[j]) {                                                     \
                const int gr  = (htile) - 1 + srow[j];                       \
                const bool rok = ((unsigned)gr < (unsigned)HH);              \
                const bool me = rok && oke[j];                               \
                const bool mo = rok && oko[j];                               \
                float e0 = me ? bk[j][0].x : 0.0f, o0 = mo ? bk[j][0].y : 0.0f; \
                float e1 = me ? bk[j][1].x : 0.0f, o1 = mo ? bk[j][1].y : 0.0f; \
                float e2 = me ? bk[j][2].x : 0.0f, o2 = mo ? bk[j][2].y : 0.0f; \
                float e3 = me ? bk[j][3].x : 0.0f, o3 = mo ? bk[j][3].y : 0.0f; \
                float e4 = me ? bk[j][4].x : 0.0f, o4 = mo ? bk[j][4].y : 0.0f; \
                float e5 = me ? bk[j][5].x : 0.0f, o5 = mo ? bk[j][5].y : 0.0f; \
                float e6 = me ? bk[j][6].x : 0.0f, o6 = mo ? bk[j][6].y : 0.0f; \
                float e7 = me ? bk[j][7].x : 0.0f, o7 = mo ? bk[j][7].y : 0.0f; \
                int4 pE, pO;                                                 \
                pE.x = pk2(e0, e1); pE.y = pk2(e2, e3);                      \
                pE.z = pk2(e4, e5); pE.w = pk2(e6, e7);                      \
                pO.x = pk2(o0, o1); pO.y = pk2(o2, o3);                      \
                pO.z = pk2(o4, o5); pO.w = pk2(o6, o7);                      \
                (bfb)[ubase[j]]     = pE;                                    \
                (bfb)[ubase[j] + 1] = pO;                                    \
            }                                                                \
        }                                                                    \
    }

    // 2-row packed compute (verified r16)
#define BODY(htile, bsrc)                                                    \
    {                                                                        \
        f32x4 acc[4];                                                        \
        _Pragma("unroll")                                                    \
        for (int wt = 0; wt < 4; ++wt) {                                     \
            acc[wt].x = bv; acc[wt].y = bv; acc[wt].z = bv; acc[wt].w = bv;  \
        }                                                                    \
        const int ub = (2 * wv) * UROW + l15;                                \
        _Pragma("unroll")                                                    \
        for (int wt = 0; wt < 4; ++wt) {                                     \
            const int u = ub + wt * 16;                                      \
            short8 a0 = *reinterpret_cast<const short8*>(&(bsrc)[u + off0]); \
            short8 a1 = *reinterpret_cast<const short8*>(&(bsrc)[u + off1]); \
            short8 a2 = *reinterpret_cast<const short8*>(&(bsrc)[u + off2]); \
            f32x4 c = acc[wt];                                               \
            c = __builtin_amdgcn_mfma_f32_16x16x32_bf16(a0, b0, c, 0, 0, 0); \
            c = __builtin_amdgcn_mfma_f32_16x16x32_bf16(a1, b1, c, 0, 0, 0); \
            c = __builtin_amdgcn_mfma_f32_16x16x32_bf16(a2, b2, c, 0, 0, 0); \
            acc[wt] = c;                                                     \
        }                                                                    \
        float* op = out + ((size_t)n * 8 + co8) * HWsz                       \
                        + (size_t)((htile) + 2 * wv + hi) * WW + w0 + ch * 4;\
        _Pragma("unroll")                                                    \
        for (int wt = 0; wt < 4; ++wt)                                       \
            *reinterpret_cast<float4*>(op + wt * 16) =                       \
                *reinterpret_cast<const float4*>(&acc[wt]);                  \
    }

    // ---- prologue ----
    LOADS(htbase, bkA);

    for (int k = 0; k < NIT; k += 2) {
        // ======== even: consume A, prefetch into B ========
        {
            const int ht = htbase + k * HB;
            LOADS(ht + HB, bkB);                       // tile k+1
            if (k == 0) {
                asm volatile("s_waitcnt vmcnt(16)" ::: "memory");
            } else {
                asm volatile("s_waitcnt vmcnt(20)" ::: "memory");
            }
            __builtin_amdgcn_sched_barrier(0);
            CONV(ht, bkA, bfA);
            asm volatile("s_waitcnt lgkmcnt(0)" ::: "memory");
            __builtin_amdgcn_sched_barrier(0);
            __builtin_amdgcn_s_barrier();
            BODY(ht, bfA);
        }
        // ======== odd: consume B, prefetch into A ========
        {
            const int ht = htbase + (k + 1) * HB;
            int t2 = k + 2; if (t2 > NIT - 1) t2 = NIT - 1;   // clamp tail
            LOADS(htbase + t2 * HB, bkA);              // tile k+2
            asm volatile("s_waitcnt vmcnt(20)" ::: "memory");
            __builtin_amdgcn_sched_barrier(0);
            CONV(ht, bkB, bfB);
            asm volatile("s_waitcnt lgkmcnt(0)" ::: "memory");
            __builtin_amdgcn_sched_barrier(0);
            __builtin_amdgcn_s_barrier();
            BODY(ht, bfB);
        }
    }
#undef LOADS
#undef CONV
#undef BODY
}

extern "C" void kernel_launch(void* const* d_in, const int* in_sizes, int n_in,
                              void* d_out, int out_size, void* d_ws, size_t ws_size,
                              hipStream_t stream) {
    const float* x    = (const float*)d_in[0];
    const float* wgt  = (const float*)d_in[1];
    const float* bias = (const float*)d_in[2];
    float* out = (float*)d_out;

    dim3 grid(16, 8, 16);   // (wx, strip, n) = 2048 blocks
    dim3 block(256, 1, 1);
    conv3x3_w2f<<<grid, block, 0, stream>>>(x, wgt, bias, out);
}